// Round 2
// baseline (186.801 us; speedup 1.0000x reference)
//
#include <hip/hip_runtime.h>

// DPQ network: response argmax (f32, packed-FP32 FMA) + codebook-gather GEMM (bf16 MFMA)
// B=32768, C=32, K=256, D_SUB=16, D_IN=512, D_OUT=512

#define NB 32768
#define NC 32
#define NK 256
#define NDS 16
#define NDIN 512
#define NDOUT 512

typedef __attribute__((ext_vector_type(8))) short s8v;   // 8 bf16 in 4 VGPRs
typedef __attribute__((ext_vector_type(4))) float f4v;   // MFMA accumulator
typedef __attribute__((ext_vector_type(2))) float f2v;   // packed f32 pair (v_pk_*_f32)

__device__ __forceinline__ unsigned short f2bf(float f) {
  unsigned int u = __float_as_uint(f);
  u += 0x7fffu + ((u >> 16) & 1u);   // RNE
  return (unsigned short)(u >> 16);
}

__device__ __forceinline__ void gload16(const void* g, void* l) {
  __builtin_amdgcn_global_load_lds(
      (const __attribute__((address_space(1))) void*)g,
      (__attribute__((address_space(3))) void*)l, 16, 0, 0);
}

// ---------------------------------------------------------------------------
// Kernel 0: Wt[n][k] = bf16(W[k][n])  (transposed for B-operand staging), and
//           centsB = bf16(centroids)  (gather source for GEMM A-operand)
// ---------------------------------------------------------------------------
__global__ __launch_bounds__(256) void k_prep(const float* __restrict__ W,
                                              const float* __restrict__ cents,
                                              unsigned short* __restrict__ Wt,
                                              unsigned short* __restrict__ centsB) {
  const int t = threadIdx.x;
  const int bid = blockIdx.x;
  if (bid < 256) {
    // 32x32 tile transpose of W (512x512)
    __shared__ float tile[32][33];
    const int k0 = (bid >> 4) << 5;
    const int n0 = (bid & 15) << 5;
    const int tx = t & 31, ty = t >> 5;  // 32 x 8
#pragma unroll
    for (int i = 0; i < 4; ++i) {
      int r = ty + i * 8;
      tile[r][tx] = W[(size_t)(k0 + r) * NDOUT + n0 + tx];
    }
    __syncthreads();
#pragma unroll
    for (int i = 0; i < 4; ++i) {
      int r = ty + i * 8;
      Wt[(size_t)(n0 + r) * NDIN + k0 + tx] = f2bf(tile[tx][r]);
    }
  } else {
    // cast centroids: 131072 floats, blocks 256..287, 16 per thread
    const int i0 = (bid - 256) * 4096 + t * 16;
#pragma unroll
    for (int j = 0; j < 4; ++j) {
      float4 v = *(const float4*)(cents + i0 + j * 4);
      unsigned short h0 = f2bf(v.x), h1 = f2bf(v.y), h2 = f2bf(v.z), h3 = f2bf(v.w);
      ushort4 h = make_ushort4(h0, h1, h2, h3);
      *(ushort4*)(centsB + i0 + j * 4) = h;
    }
  }
}

// ---------------------------------------------------------------------------
// Kernel 1: per (b,c): response = <inputs[b,c,:], centroids[c,k,:]>, max/argmax
// block = 1024 b-values x 1 c; 4 b per thread; centroids[c] in LDS (16 KiB).
// Inner product via packed-FP32 FMA (v_pk_fma_f32): 8 pk-FMAs per (b,k)
// instead of 16 scalar FMAs. Accumulator grouping: acc0 holds d={0,1,4,5,...},
// acc1 holds d={2,3,6,7,...}; final sum (acc.x+acc.y) — ~1e-6 rel reorder
// error, same class as the validated scalar version (codes unaffected).
// ---------------------------------------------------------------------------
__global__ __launch_bounds__(256) void k_phase1(const float* __restrict__ inputs,
                                                const float* __restrict__ cents,
                                                float* __restrict__ negout,
                                                float* __restrict__ codefout,
                                                int* __restrict__ codeint) {
  __shared__ float4 lc[NK * 4];  // 256 k x 16 floats = 16 KiB
  const int t = threadIdx.x;
  const int c = blockIdx.y;
  {
    const float4* cg = (const float4*)(cents + (size_t)c * NK * NDS);
#pragma unroll
    for (int i = 0; i < 4; ++i) lc[t + i * 256] = cg[t + i * 256];
  }
  __syncthreads();

  const int b0 = blockIdx.x * 1024 + t;
  f2v in[4][8];
#pragma unroll
  for (int i = 0; i < 4; ++i) {
    const float4* ip = (const float4*)(inputs + ((size_t)(b0 + i * 256) * NC + c) * NDS);
#pragma unroll
    for (int j = 0; j < 4; ++j) {
      float4 v = ip[j];
      in[i][j * 2 + 0] = f2v{v.x, v.y};
      in[i][j * 2 + 1] = f2v{v.z, v.w};
    }
  }

  float best[4];
  int bk[4];
#pragma unroll
  for (int i = 0; i < 4; ++i) { best[i] = -3.0e38f; bk[i] = 0; }

#pragma unroll 2
  for (int k = 0; k < NK; ++k) {
    f2v cv[8];
    float4 q0 = lc[k * 4 + 0]; cv[0] = f2v{q0.x, q0.y}; cv[1] = f2v{q0.z, q0.w};
    float4 q1 = lc[k * 4 + 1]; cv[2] = f2v{q1.x, q1.y}; cv[3] = f2v{q1.z, q1.w};
    float4 q2 = lc[k * 4 + 2]; cv[4] = f2v{q2.x, q2.y}; cv[5] = f2v{q2.z, q2.w};
    float4 q3 = lc[k * 4 + 3]; cv[6] = f2v{q3.x, q3.y}; cv[7] = f2v{q3.z, q3.w};
#pragma unroll
    for (int i = 0; i < 4; ++i) {
      f2v a0 = in[i][0] * cv[0];                               // v_pk_mul_f32
      f2v a1 = in[i][1] * cv[1];
#pragma unroll
      for (int j = 2; j < 8; j += 2) {
        a0 = __builtin_elementwise_fma(in[i][j], cv[j], a0);   // v_pk_fma_f32
        a1 = __builtin_elementwise_fma(in[i][j + 1], cv[j + 1], a1);
      }
      float dot = (a0.x + a0.y) + (a1.x + a1.y);
      if (dot > best[i]) { best[i] = dot; bk[i] = k; }  // strict > => first-index tie
    }
  }

#pragma unroll
  for (int i = 0; i < 4; ++i) {
    size_t o = (size_t)(b0 + i * 256) * NC + c;
    negout[o] = -best[i];
    codefout[o] = (float)bk[i];
    codeint[o] = bk[i];
  }
}

// ---------------------------------------------------------------------------
// Kernel 2: product = gather(centsB, codes) @ W   via bf16 MFMA
// 128x128 tile, BK=64, 4 waves (2x2 of 64x64), A gathered via global_load_lds
// ---------------------------------------------------------------------------
__global__ __launch_bounds__(256) void k_gemm(const unsigned short* __restrict__ centsB,
                                              const int* __restrict__ codeint,
                                              const unsigned short* __restrict__ Wt,
                                              float* __restrict__ out) {
  __shared__ __align__(16) unsigned short As[128 * 64];  // 16 KiB (XOR-swizzled)
  __shared__ __align__(16) unsigned short Bs[128 * 64];  // 16 KiB (XOR-swizzled)
  __shared__ int lcode[128 * 33];                        // codes, padded vs bank conflict

  const int t = threadIdx.x;
  const int l = t & 63;
  const int w = t >> 6;
  const int wm = w >> 1, wn = w & 1;
  const int m0 = blockIdx.x * 128;
  const int n0 = blockIdx.y * 128;

  // preload this block's codes: rows m0..m0+127, all 32 c (coalesced int4)
  {
    const int4* cp = (const int4*)(codeint + (size_t)m0 * NC);
#pragma unroll
    for (int i = 0; i < 4; ++i) {
      int idx = t + i * 256;          // int4 index; row = idx/8, col = (idx%8)*4
      int4 v = cp[idx];
      int row = idx >> 3, col = (idx & 7) * 4;
      lcode[row * 33 + col + 0] = v.x;
      lcode[row * 33 + col + 1] = v.y;
      lcode[row * 33 + col + 2] = v.z;
      lcode[row * 33 + col + 3] = v.w;
    }
  }

  f4v acc[4][4] = {};
  const int s = t & 7;        // 16B slot within a 128B row
  const int rq = t >> 3;      // 0..31: row within a 32-row staging chunk

  for (int kt = 0; kt < 8; ++kt) {
    __syncthreads();  // iter0: lcode visible; later: all frag reads of As/Bs done
    const int c0 = kt * 4;
    // ---- stage A (gathered): As[row][slot] = A[m0+row][kt*64 + (slot^(row&7))*8 ..]
#pragma unroll
    for (int i = 0; i < 4; ++i) {
      int lr = i * 32 + rq;
      int srcslot = s ^ (lr & 7);
      int cl = srcslot >> 1, half = srcslot & 1;
      int code = lcode[lr * 33 + c0 + cl];
      const unsigned short* gsrc =
          centsB + ((size_t)((c0 + cl) * NK + code) * NDS + half * 8);
      gload16(gsrc, (char*)As + i * 4096 + (w << 10));
    }
    // ---- stage B: Bs[n][slot] = Wt[n0+n][kt*64 + (slot^(n&7))*8 ..]
#pragma unroll
    for (int i = 0; i < 4; ++i) {
      int lr = i * 32 + rq;
      int k16 = s ^ (lr & 7);
      const unsigned short* gsrc = Wt + (size_t)(n0 + lr) * NDIN + kt * 64 + k16 * 8;
      gload16(gsrc, (char*)Bs + i * 4096 + (w << 10));
    }
    __syncthreads();  // compiler inserts vmcnt(0) drain: LDS tiles ready

    s8v af[4][2], bfr[4][2];
#pragma unroll
    for (int mf = 0; mf < 4; ++mf)
#pragma unroll
      for (int ks = 0; ks < 2; ++ks) {
        int row = wm * 64 + mf * 16 + (l & 15);
        int slot = ks * 4 + (l >> 4);
        af[mf][ks] = *(const s8v*)((const char*)As + row * 128 + ((slot ^ (row & 7)) << 4));
      }
#pragma unroll
    for (int nf = 0; nf < 4; ++nf)
#pragma unroll
      for (int ks = 0; ks < 2; ++ks) {
        int row = wn * 64 + nf * 16 + (l & 15);
        int slot = ks * 4 + (l >> 4);
        bfr[nf][ks] = *(const s8v*)((const char*)Bs + row * 128 + ((slot ^ (row & 7)) << 4));
      }
#pragma unroll
    for (int ks = 0; ks < 2; ++ks)
#pragma unroll
      for (int mf = 0; mf < 4; ++mf)
#pragma unroll
        for (int nf = 0; nf < 4; ++nf)
          acc[mf][nf] = __builtin_amdgcn_mfma_f32_16x16x32_bf16(
              af[mf][ks], bfr[nf][ks], acc[mf][nf], 0, 0, 0);
  }

  // epilogue: C[row][col], row=(l>>4)*4+r, col=l&15 within each 16x16 frag
#pragma unroll
  for (int mf = 0; mf < 4; ++mf)
#pragma unroll
    for (int nf = 0; nf < 4; ++nf)
#pragma unroll
      for (int r = 0; r < 4; ++r) {
        int row = m0 + wm * 64 + mf * 16 + (l >> 4) * 4 + r;
        int col = n0 + wn * 64 + nf * 16 + (l & 15);
        out[(size_t)row * NDOUT + col] = acc[mf][nf][r];
      }
}

// ---------------------------------------------------------------------------
extern "C" void kernel_launch(void* const* d_in, const int* in_sizes, int n_in,
                              void* d_out, int out_size, void* d_ws, size_t ws_size,
                              hipStream_t stream) {
  const float* inputs = (const float*)d_in[0];   // (B, C, 16) f32
  const float* cents  = (const float*)d_in[1];   // (C, K, 16) f32
  const float* W      = (const float*)d_in[2];   // (512, 512) f32

  float* out = (float*)d_out;
  float* negout   = out + (size_t)NB * NDOUT;            // (B, C)
  float* codefout = negout + (size_t)NB * NC;            // (B, C) as float values

  unsigned short* Wt     = (unsigned short*)d_ws;                          // 512 KiB
  unsigned short* centsB = (unsigned short*)((char*)d_ws + 512 * 1024);    // 256 KiB
  int* codeint           = (int*)((char*)d_ws + (1 << 20));                // 4 MiB

  k_prep<<<288, 256, 0, stream>>>(W, cents, Wt, centsB);
  k_phase1<<<dim3(NB / 1024, NC), 256, 0, stream>>>(inputs, cents, negout, codefout, codeint);
  k_gemm<<<dim3(NB / 128, NDOUT / 128), 256, 0, stream>>>(centsB, codeint, Wt, out);
}

// Round 3
// 181.756 us; speedup vs baseline: 1.0278x; 1.0278x over previous
//
#include <hip/hip_runtime.h>

// DPQ network: response argmax (packed-f32 FMA, SGPR centroids) + codebook-gather GEMM (bf16 MFMA)
// B=32768, C=32, K=256, D_SUB=16, D_IN=512, D_OUT=512

#define NB 32768
#define NC 32
#define NK 256
#define NDS 16
#define NDIN 512
#define NDOUT 512

typedef __attribute__((ext_vector_type(8))) short s8v;   // 8 bf16 in 4 VGPRs
typedef __attribute__((ext_vector_type(4))) float f4v;   // MFMA accumulator
typedef __attribute__((ext_vector_type(2))) float f2v;   // packed f32 pair (v_pk_*_f32)

__device__ __forceinline__ unsigned short f2bf(float f) {
  unsigned int u = __float_as_uint(f);
  u += 0x7fffu + ((u >> 16) & 1u);   // RNE
  return (unsigned short)(u >> 16);
}

__device__ __forceinline__ void gload16(const void* g, void* l) {
  __builtin_amdgcn_global_load_lds(
      (const __attribute__((address_space(1))) void*)g,
      (__attribute__((address_space(3))) void*)l, 16, 0, 0);
}

// ---------------------------------------------------------------------------
// Kernel 0: Wt[n][k] = bf16(W[k][n])  (transposed for B-operand staging), and
//           centsB = bf16(centroids)  (gather source for GEMM A-operand)
// ---------------------------------------------------------------------------
__global__ __launch_bounds__(256) void k_prep(const float* __restrict__ W,
                                              const float* __restrict__ cents,
                                              unsigned short* __restrict__ Wt,
                                              unsigned short* __restrict__ centsB) {
  const int t = threadIdx.x;
  const int bid = blockIdx.x;
  if (bid < 256) {
    // 32x32 tile transpose of W (512x512)
    __shared__ float tile[32][33];
    const int k0 = (bid >> 4) << 5;
    const int n0 = (bid & 15) << 5;
    const int tx = t & 31, ty = t >> 5;  // 32 x 8
#pragma unroll
    for (int i = 0; i < 4; ++i) {
      int r = ty + i * 8;
      tile[r][tx] = W[(size_t)(k0 + r) * NDOUT + n0 + tx];
    }
    __syncthreads();
#pragma unroll
    for (int i = 0; i < 4; ++i) {
      int r = ty + i * 8;
      Wt[(size_t)(n0 + r) * NDIN + k0 + tx] = f2bf(tile[tx][r]);
    }
  } else {
    // cast centroids: 131072 floats, blocks 256..287, 16 per thread
    const int i0 = (bid - 256) * 4096 + t * 16;
#pragma unroll
    for (int j = 0; j < 4; ++j) {
      float4 v = *(const float4*)(cents + i0 + j * 4);
      unsigned short h0 = f2bf(v.x), h1 = f2bf(v.y), h2 = f2bf(v.z), h3 = f2bf(v.w);
      ushort4 h = make_ushort4(h0, h1, h2, h3);
      *(ushort4*)(centsB + i0 + j * 4) = h;
    }
  }
}

// ---------------------------------------------------------------------------
// Kernel 1: per (b,c): response = <inputs[b,c,:], centroids[c,k,:]>, max/argmax
// 2 b-values per thread (named f2v registers only — NO arrays, NO LDS).
// Centroid address depends only on (blockIdx.y, k) -> uniform -> s_load
// broadcast; worst case L1-broadcast vector load (16 KB per c fits L1).
// Dot via v_pk_fma_f32: acc0 covers d={0,1,4,5,8,9,12,13}, acc1 the rest;
// dot = (acc0.x+acc0.y)+(acc1.x+acc1.y) — same grouping as the R2 version
// that passed correctness (codes unaffected). Strict > keeps first-index tie.
// ---------------------------------------------------------------------------
__global__ __launch_bounds__(256) void k_phase1(const float* __restrict__ inputs,
                                                const float* __restrict__ cents,
                                                float* __restrict__ negout,
                                                float* __restrict__ codefout,
                                                int* __restrict__ codeint) {
  const int t = threadIdx.x;
  const int c = blockIdx.y;
  const int b0 = blockIdx.x * 512 + t;      // this thread: b0 and b0+256

  f2v ia0, ia1, ia2, ia3, ia4, ia5, ia6, ia7;
  f2v ib0, ib1, ib2, ib3, ib4, ib5, ib6, ib7;
  {
    const float4* ipA = (const float4*)(inputs + ((size_t)b0 * NC + c) * NDS);
    const float4* ipB = (const float4*)(inputs + ((size_t)(b0 + 256) * NC + c) * NDS);
    float4 v;
    v = ipA[0]; ia0 = f2v{v.x, v.y}; ia1 = f2v{v.z, v.w};
    v = ipA[1]; ia2 = f2v{v.x, v.y}; ia3 = f2v{v.z, v.w};
    v = ipA[2]; ia4 = f2v{v.x, v.y}; ia5 = f2v{v.z, v.w};
    v = ipA[3]; ia6 = f2v{v.x, v.y}; ia7 = f2v{v.z, v.w};
    v = ipB[0]; ib0 = f2v{v.x, v.y}; ib1 = f2v{v.z, v.w};
    v = ipB[1]; ib2 = f2v{v.x, v.y}; ib3 = f2v{v.z, v.w};
    v = ipB[2]; ib4 = f2v{v.x, v.y}; ib5 = f2v{v.z, v.w};
    v = ipB[3]; ib6 = f2v{v.x, v.y}; ib7 = f2v{v.z, v.w};
  }

  float bestA = -3.0e38f, bestB = -3.0e38f;
  int bkA = 0, bkB = 0;
  const float* cw = cents + (size_t)c * NK * NDS;   // uniform across the block

#pragma unroll 4
  for (int k = 0; k < NK; ++k) {
    const float* p = cw + k * NDS;                  // uniform -> s_load candidate
    f2v c0 = f2v{p[0], p[1]},   c1 = f2v{p[2], p[3]};
    f2v c2 = f2v{p[4], p[5]},   c3 = f2v{p[6], p[7]};
    f2v c4 = f2v{p[8], p[9]},   c5 = f2v{p[10], p[11]};
    f2v c6 = f2v{p[12], p[13]}, c7 = f2v{p[14], p[15]};

    f2v sa0 = ia0 * c0, sa1 = ia1 * c1;
    sa0 = __builtin_elementwise_fma(ia2, c2, sa0);
    sa1 = __builtin_elementwise_fma(ia3, c3, sa1);
    sa0 = __builtin_elementwise_fma(ia4, c4, sa0);
    sa1 = __builtin_elementwise_fma(ia5, c5, sa1);
    sa0 = __builtin_elementwise_fma(ia6, c6, sa0);
    sa1 = __builtin_elementwise_fma(ia7, c7, sa1);
    float dA = (sa0.x + sa0.y) + (sa1.x + sa1.y);

    f2v sb0 = ib0 * c0, sb1 = ib1 * c1;
    sb0 = __builtin_elementwise_fma(ib2, c2, sb0);
    sb1 = __builtin_elementwise_fma(ib3, c3, sb1);
    sb0 = __builtin_elementwise_fma(ib4, c4, sb0);
    sb1 = __builtin_elementwise_fma(ib5, c5, sb1);
    sb0 = __builtin_elementwise_fma(ib6, c6, sb0);
    sb1 = __builtin_elementwise_fma(ib7, c7, sb1);
    float dB = (sb0.x + sb0.y) + (sb1.x + sb1.y);

    if (dA > bestA) { bestA = dA; bkA = k; }   // strict > => first-index tie
    if (dB > bestB) { bestB = dB; bkB = k; }
  }

  {
    size_t oA = (size_t)b0 * NC + c;
    size_t oB = (size_t)(b0 + 256) * NC + c;
    negout[oA] = -bestA;  codefout[oA] = (float)bkA;  codeint[oA] = bkA;
    negout[oB] = -bestB;  codefout[oB] = (float)bkB;  codeint[oB] = bkB;
  }
}

// ---------------------------------------------------------------------------
// Kernel 2: product = gather(centsB, codes) @ W   via bf16 MFMA
// 128x128 tile, BK=64, 4 waves (2x2 of 64x64), A gathered via global_load_lds
// ---------------------------------------------------------------------------
__global__ __launch_bounds__(256) void k_gemm(const unsigned short* __restrict__ centsB,
                                              const int* __restrict__ codeint,
                                              const unsigned short* __restrict__ Wt,
                                              float* __restrict__ out) {
  __shared__ __align__(16) unsigned short As[128 * 64];  // 16 KiB (XOR-swizzled)
  __shared__ __align__(16) unsigned short Bs[128 * 64];  // 16 KiB (XOR-swizzled)
  __shared__ int lcode[128 * 33];                        // codes, padded vs bank conflict

  const int t = threadIdx.x;
  const int l = t & 63;
  const int w = t >> 6;
  const int wm = w >> 1, wn = w & 1;
  const int m0 = blockIdx.x * 128;
  const int n0 = blockIdx.y * 128;

  // preload this block's codes: rows m0..m0+127, all 32 c (coalesced int4)
  {
    const int4* cp = (const int4*)(codeint + (size_t)m0 * NC);
#pragma unroll
    for (int i = 0; i < 4; ++i) {
      int idx = t + i * 256;          // int4 index; row = idx/8, col = (idx%8)*4
      int4 v = cp[idx];
      int row = idx >> 3, col = (idx & 7) * 4;
      lcode[row * 33 + col + 0] = v.x;
      lcode[row * 33 + col + 1] = v.y;
      lcode[row * 33 + col + 2] = v.z;
      lcode[row * 33 + col + 3] = v.w;
    }
  }

  f4v acc[4][4] = {};
  const int s = t & 7;        // 16B slot within a 128B row
  const int rq = t >> 3;      // 0..31: row within a 32-row staging chunk

  for (int kt = 0; kt < 8; ++kt) {
    __syncthreads();  // iter0: lcode visible; later: all frag reads of As/Bs done
    const int c0 = kt * 4;
    // ---- stage A (gathered): As[row][slot] = A[m0+row][kt*64 + (slot^(row&7))*8 ..]
#pragma unroll
    for (int i = 0; i < 4; ++i) {
      int lr = i * 32 + rq;
      int srcslot = s ^ (lr & 7);
      int cl = srcslot >> 1, half = srcslot & 1;
      int code = lcode[lr * 33 + c0 + cl];
      const unsigned short* gsrc =
          centsB + ((size_t)((c0 + cl) * NK + code) * NDS + half * 8);
      gload16(gsrc, (char*)As + i * 4096 + (w << 10));
    }
    // ---- stage B: Bs[n][slot] = Wt[n0+n][kt*64 + (slot^(n&7))*8 ..]
#pragma unroll
    for (int i = 0; i < 4; ++i) {
      int lr = i * 32 + rq;
      int k16 = s ^ (lr & 7);
      const unsigned short* gsrc = Wt + (size_t)(n0 + lr) * NDIN + kt * 64 + k16 * 8;
      gload16(gsrc, (char*)Bs + i * 4096 + (w << 10));
    }
    __syncthreads();  // compiler inserts vmcnt(0) drain: LDS tiles ready

    s8v af[4][2], bfr[4][2];
#pragma unroll
    for (int mf = 0; mf < 4; ++mf)
#pragma unroll
      for (int ks = 0; ks < 2; ++ks) {
        int row = wm * 64 + mf * 16 + (l & 15);
        int slot = ks * 4 + (l >> 4);
        af[mf][ks] = *(const s8v*)((const char*)As + row * 128 + ((slot ^ (row & 7)) << 4));
      }
#pragma unroll
    for (int nf = 0; nf < 4; ++nf)
#pragma unroll
      for (int ks = 0; ks < 2; ++ks) {
        int row = wn * 64 + nf * 16 + (l & 15);
        int slot = ks * 4 + (l >> 4);
        bfr[nf][ks] = *(const s8v*)((const char*)Bs + row * 128 + ((slot ^ (row & 7)) << 4));
      }
#pragma unroll
    for (int ks = 0; ks < 2; ++ks)
#pragma unroll
      for (int mf = 0; mf < 4; ++mf)
#pragma unroll
        for (int nf = 0; nf < 4; ++nf)
          acc[mf][nf] = __builtin_amdgcn_mfma_f32_16x16x32_bf16(
              af[mf][ks], bfr[nf][ks], acc[mf][nf], 0, 0, 0);
  }

  // epilogue: C[row][col], row=(l>>4)*4+r, col=l&15 within each 16x16 frag
#pragma unroll
  for (int mf = 0; mf < 4; ++mf)
#pragma unroll
    for (int nf = 0; nf < 4; ++nf)
#pragma unroll
      for (int r = 0; r < 4; ++r) {
        int row = m0 + wm * 64 + mf * 16 + (l >> 4) * 4 + r;
        int col = n0 + wn * 64 + nf * 16 + (l & 15);
        out[(size_t)row * NDOUT + col] = acc[mf][nf][r];
      }
}

// ---------------------------------------------------------------------------
extern "C" void kernel_launch(void* const* d_in, const int* in_sizes, int n_in,
                              void* d_out, int out_size, void* d_ws, size_t ws_size,
                              hipStream_t stream) {
  const float* inputs = (const float*)d_in[0];   // (B, C, 16) f32
  const float* cents  = (const float*)d_in[1];   // (C, K, 16) f32
  const float* W      = (const float*)d_in[2];   // (512, 512) f32

  float* out = (float*)d_out;
  float* negout   = out + (size_t)NB * NDOUT;            // (B, C)
  float* codefout = negout + (size_t)NB * NC;            // (B, C) as float values

  unsigned short* Wt     = (unsigned short*)d_ws;                          // 512 KiB
  unsigned short* centsB = (unsigned short*)((char*)d_ws + 512 * 1024);    // 256 KiB
  int* codeint           = (int*)((char*)d_ws + (1 << 20));                // 4 MiB

  k_prep<<<288, 256, 0, stream>>>(W, cents, Wt, centsB);
  k_phase1<<<dim3(NB / 512, NC), 256, 0, stream>>>(inputs, cents, negout, codefout, codeint);
  k_gemm<<<dim3(NB / 128, NDOUT / 128), 256, 0, stream>>>(centsB, codeint, Wt, out);
}

// Round 4
// 159.408 us; speedup vs baseline: 1.1718x; 1.1402x over previous
//
#include <hip/hip_runtime.h>

// DPQ network: response argmax (k-paired packed-f32 FMA) + codebook-gather GEMM (bf16 MFMA)
// B=32768, C=32, K=256, D_SUB=16, D_IN=512, D_OUT=512

#define NB 32768
#define NC 32
#define NK 256
#define NDS 16
#define NDIN 512
#define NDOUT 512

typedef __attribute__((ext_vector_type(8))) short s8v;   // 8 bf16 in 4 VGPRs
typedef __attribute__((ext_vector_type(4))) float f4v;   // MFMA accumulator
typedef __attribute__((ext_vector_type(2))) float f2v;   // packed f32 pair (v_pk_*_f32)

__device__ __forceinline__ unsigned short f2bf(float f) {
  unsigned int u = __float_as_uint(f);
  u += 0x7fffu + ((u >> 16) & 1u);   // RNE
  return (unsigned short)(u >> 16);
}

__device__ __forceinline__ void gload16(const void* g, void* l) {
  __builtin_amdgcn_global_load_lds(
      (const __attribute__((address_space(1))) void*)g,
      (__attribute__((address_space(3))) void*)l, 16, 0, 0);
}

// pinned packed-f32 codegen; b is wave-uniform (SGPR pair), a per-lane (VGPR pair)
#define PKMUL(acc, a, b) asm("v_pk_mul_f32 %0, %1, %2"     : "=v"(acc) : "v"(a), "s"(b))
#define PKFMA(acc, a, b) asm("v_pk_fma_f32 %0, %1, %2, %0" : "+v"(acc) : "v"(a), "s"(b))

// ---------------------------------------------------------------------------
// Kernel 0: Wt[n][k] = bf16(W[k][n]); centsB = bf16(centroids);
//           centsP[c][kp][d] = {cents[c][2kp][d], cents[c][2kp+1][d]}  (f2v)
// ---------------------------------------------------------------------------
__global__ __launch_bounds__(256) void k_prep(const float* __restrict__ W,
                                              const float* __restrict__ cents,
                                              unsigned short* __restrict__ Wt,
                                              unsigned short* __restrict__ centsB,
                                              f2v* __restrict__ centsP) {
  const int t = threadIdx.x;
  const int bid = blockIdx.x;
  if (bid < 256) {
    // 32x32 tile transpose of W (512x512)
    __shared__ float tile[32][33];
    const int k0 = (bid >> 4) << 5;
    const int n0 = (bid & 15) << 5;
    const int tx = t & 31, ty = t >> 5;  // 32 x 8
#pragma unroll
    for (int i = 0; i < 4; ++i) {
      int r = ty + i * 8;
      tile[r][tx] = W[(size_t)(k0 + r) * NDOUT + n0 + tx];
    }
    __syncthreads();
#pragma unroll
    for (int i = 0; i < 4; ++i) {
      int r = ty + i * 8;
      Wt[(size_t)(n0 + r) * NDIN + k0 + tx] = f2bf(tile[tx][r]);
    }
  } else if (bid < 288) {
    // cast centroids: 131072 floats, blocks 256..287, 16 per thread
    const int i0 = (bid - 256) * 4096 + t * 16;
#pragma unroll
    for (int j = 0; j < 4; ++j) {
      float4 v = *(const float4*)(cents + i0 + j * 4);
      unsigned short h0 = f2bf(v.x), h1 = f2bf(v.y), h2 = f2bf(v.z), h3 = f2bf(v.w);
      ushort4 h = make_ushort4(h0, h1, h2, h3);
      *(ushort4*)(centsB + i0 + j * 4) = h;
    }
  } else {
    // k-pair packing for phase1: blocks 288..319, one per c
    const int c = bid - 288;
    const int kp = t & 127;
    const int d0 = (t >> 7) * 8;
    const float* r0 = cents + ((size_t)c * NK + 2 * kp) * NDS + d0;
    const float* r1 = r0 + NDS;
    f2v* dst = centsP + ((size_t)c * 128 + kp) * NDS + d0;
#pragma unroll
    for (int j = 0; j < 8; ++j) dst[j] = f2v{r0[j], r1[j]};
  }
}

// ---------------------------------------------------------------------------
// Kernel 1: per (b,c): response = <inputs[b,c,:], centroids[c,k,:]>, max/argmax
// 2 b's per thread. Centroids pre-packed as k-pairs: one v_pk_fma_f32 advances
// one d for two k's; each dot finishes in its own register half -> no
// horizontal adds. Centroid pairs are block-uniform -> SGPR (s_load).
// Dot order: sequential left fold d=0..15 (f32+fma, rounding class identical
// to prior passing versions). Strict > compare, k even then odd: first-index tie.
// ---------------------------------------------------------------------------
__global__ __launch_bounds__(256) void k_phase1(const float* __restrict__ inputs,
                                                const f2v* __restrict__ centsP,
                                                float* __restrict__ negout,
                                                float* __restrict__ codefout,
                                                int* __restrict__ codeint) {
  const int t = threadIdx.x;
  const int c = blockIdx.y;
  const int b0 = blockIdx.x * 512 + t;      // this thread: b0 and b0+256

  // broadcast pairs (x==y) for 2 b's, named registers only
  f2v A0, A1, A2, A3, A4, A5, A6, A7, A8, A9, A10, A11, A12, A13, A14, A15;
  f2v B0, B1, B2, B3, B4, B5, B6, B7, B8, B9, B10, B11, B12, B13, B14, B15;
  {
    const float4* ipA = (const float4*)(inputs + ((size_t)b0 * NC + c) * NDS);
    const float4* ipB = (const float4*)(inputs + ((size_t)(b0 + 256) * NC + c) * NDS);
    float4 v;
    v = ipA[0]; A0 = f2v{v.x, v.x}; A1 = f2v{v.y, v.y}; A2 = f2v{v.z, v.z}; A3 = f2v{v.w, v.w};
    v = ipA[1]; A4 = f2v{v.x, v.x}; A5 = f2v{v.y, v.y}; A6 = f2v{v.z, v.z}; A7 = f2v{v.w, v.w};
    v = ipA[2]; A8 = f2v{v.x, v.x}; A9 = f2v{v.y, v.y}; A10 = f2v{v.z, v.z}; A11 = f2v{v.w, v.w};
    v = ipA[3]; A12 = f2v{v.x, v.x}; A13 = f2v{v.y, v.y}; A14 = f2v{v.z, v.z}; A15 = f2v{v.w, v.w};
    v = ipB[0]; B0 = f2v{v.x, v.x}; B1 = f2v{v.y, v.y}; B2 = f2v{v.z, v.z}; B3 = f2v{v.w, v.w};
    v = ipB[1]; B4 = f2v{v.x, v.x}; B5 = f2v{v.y, v.y}; B6 = f2v{v.z, v.z}; B7 = f2v{v.w, v.w};
    v = ipB[2]; B8 = f2v{v.x, v.x}; B9 = f2v{v.y, v.y}; B10 = f2v{v.z, v.z}; B11 = f2v{v.w, v.w};
    v = ipB[3]; B12 = f2v{v.x, v.x}; B13 = f2v{v.y, v.y}; B14 = f2v{v.z, v.z}; B15 = f2v{v.w, v.w};
  }

  float bestA = -3.0e38f, bestB = -3.0e38f;
  int bkA = 0, bkB = 0;
  const f2v* cp = centsP + (size_t)c * (128 * NDS);   // uniform across block

#pragma unroll 2
  for (int kp = 0; kp < 128; ++kp) {
    const f2v* p = cp + kp * NDS;                     // uniform -> s_load
    f2v c0 = p[0], c1 = p[1], c2 = p[2], c3 = p[3];
    f2v c4 = p[4], c5 = p[5], c6 = p[6], c7 = p[7];
    f2v c8 = p[8], c9 = p[9], c10 = p[10], c11 = p[11];
    f2v c12 = p[12], c13 = p[13], c14 = p[14], c15 = p[15];

    f2v accA, accB;
    PKMUL(accA, A0, c0);       PKMUL(accB, B0, c0);
    PKFMA(accA, A1, c1);       PKFMA(accB, B1, c1);
    PKFMA(accA, A2, c2);       PKFMA(accB, B2, c2);
    PKFMA(accA, A3, c3);       PKFMA(accB, B3, c3);
    PKFMA(accA, A4, c4);       PKFMA(accB, B4, c4);
    PKFMA(accA, A5, c5);       PKFMA(accB, B5, c5);
    PKFMA(accA, A6, c6);       PKFMA(accB, B6, c6);
    PKFMA(accA, A7, c7);       PKFMA(accB, B7, c7);
    PKFMA(accA, A8, c8);       PKFMA(accB, B8, c8);
    PKFMA(accA, A9, c9);       PKFMA(accB, B9, c9);
    PKFMA(accA, A10, c10);     PKFMA(accB, B10, c10);
    PKFMA(accA, A11, c11);     PKFMA(accB, B11, c11);
    PKFMA(accA, A12, c12);     PKFMA(accB, B12, c12);
    PKFMA(accA, A13, c13);     PKFMA(accB, B13, c13);
    PKFMA(accA, A14, c14);     PKFMA(accB, B14, c14);
    PKFMA(accA, A15, c15);     PKFMA(accB, B15, c15);

    const int k0 = kp * 2;
    if (accA.x > bestA) { bestA = accA.x; bkA = k0; }      // strict >: first-index tie
    if (accA.y > bestA) { bestA = accA.y; bkA = k0 + 1; }
    if (accB.x > bestB) { bestB = accB.x; bkB = k0; }
    if (accB.y > bestB) { bestB = accB.y; bkB = k0 + 1; }
  }

  {
    size_t oA = (size_t)b0 * NC + c;
    size_t oB = (size_t)(b0 + 256) * NC + c;
    negout[oA] = -bestA;  codefout[oA] = (float)bkA;  codeint[oA] = bkA;
    negout[oB] = -bestB;  codefout[oB] = (float)bkB;  codeint[oB] = bkB;
  }
}

// ---------------------------------------------------------------------------
// Kernel 2: product = gather(centsB, codes) @ W   via bf16 MFMA
// 128x128 tile, BK=64, 4 waves (2x2 of 64x64), A gathered via global_load_lds
// ---------------------------------------------------------------------------
__global__ __launch_bounds__(256) void k_gemm(const unsigned short* __restrict__ centsB,
                                              const int* __restrict__ codeint,
                                              const unsigned short* __restrict__ Wt,
                                              float* __restrict__ out) {
  __shared__ __align__(16) unsigned short As[128 * 64];  // 16 KiB (XOR-swizzled)
  __shared__ __align__(16) unsigned short Bs[128 * 64];  // 16 KiB (XOR-swizzled)
  __shared__ int lcode[128 * 33];                        // codes, padded vs bank conflict

  const int t = threadIdx.x;
  const int l = t & 63;
  const int w = t >> 6;
  const int wm = w >> 1, wn = w & 1;
  const int m0 = blockIdx.x * 128;
  const int n0 = blockIdx.y * 128;

  // preload this block's codes: rows m0..m0+127, all 32 c (coalesced int4)
  {
    const int4* cp = (const int4*)(codeint + (size_t)m0 * NC);
#pragma unroll
    for (int i = 0; i < 4; ++i) {
      int idx = t + i * 256;          // int4 index; row = idx/8, col = (idx%8)*4
      int4 v = cp[idx];
      int row = idx >> 3, col = (idx & 7) * 4;
      lcode[row * 33 + col + 0] = v.x;
      lcode[row * 33 + col + 1] = v.y;
      lcode[row * 33 + col + 2] = v.z;
      lcode[row * 33 + col + 3] = v.w;
    }
  }

  f4v acc[4][4] = {};
  const int s = t & 7;        // 16B slot within a 128B row
  const int rq = t >> 3;      // 0..31: row within a 32-row staging chunk

  for (int kt = 0; kt < 8; ++kt) {
    __syncthreads();  // iter0: lcode visible; later: all frag reads of As/Bs done
    const int c0 = kt * 4;
    // ---- stage A (gathered): As[row][slot] = A[m0+row][kt*64 + (slot^(row&7))*8 ..]
#pragma unroll
    for (int i = 0; i < 4; ++i) {
      int lr = i * 32 + rq;
      int srcslot = s ^ (lr & 7);
      int cl = srcslot >> 1, half = srcslot & 1;
      int code = lcode[lr * 33 + c0 + cl];
      const unsigned short* gsrc =
          centsB + ((size_t)((c0 + cl) * NK + code) * NDS + half * 8);
      gload16(gsrc, (char*)As + i * 4096 + (w << 10));
    }
    // ---- stage B: Bs[n][slot] = Wt[n0+n][kt*64 + (slot^(n&7))*8 ..]
#pragma unroll
    for (int i = 0; i < 4; ++i) {
      int lr = i * 32 + rq;
      int k16 = s ^ (lr & 7);
      const unsigned short* gsrc = Wt + (size_t)(n0 + lr) * NDIN + kt * 64 + k16 * 8;
      gload16(gsrc, (char*)Bs + i * 4096 + (w << 10));
    }
    __syncthreads();  // compiler inserts vmcnt(0) drain: LDS tiles ready

    s8v af[4][2], bfr[4][2];
#pragma unroll
    for (int mf = 0; mf < 4; ++mf)
#pragma unroll
      for (int ks = 0; ks < 2; ++ks) {
        int row = wm * 64 + mf * 16 + (l & 15);
        int slot = ks * 4 + (l >> 4);
        af[mf][ks] = *(const s8v*)((const char*)As + row * 128 + ((slot ^ (row & 7)) << 4));
      }
#pragma unroll
    for (int nf = 0; nf < 4; ++nf)
#pragma unroll
      for (int ks = 0; ks < 2; ++ks) {
        int row = wn * 64 + nf * 16 + (l & 15);
        int slot = ks * 4 + (l >> 4);
        bfr[nf][ks] = *(const s8v*)((const char*)Bs + row * 128 + ((slot ^ (row & 7)) << 4));
      }
#pragma unroll
    for (int ks = 0; ks < 2; ++ks)
#pragma unroll
      for (int mf = 0; mf < 4; ++mf)
#pragma unroll
        for (int nf = 0; nf < 4; ++nf)
          acc[mf][nf] = __builtin_amdgcn_mfma_f32_16x16x32_bf16(
              af[mf][ks], bfr[nf][ks], acc[mf][nf], 0, 0, 0);
  }

  // epilogue: C[row][col], row=(l>>4)*4+r, col=l&15 within each 16x16 frag
#pragma unroll
  for (int mf = 0; mf < 4; ++mf)
#pragma unroll
    for (int nf = 0; nf < 4; ++nf)
#pragma unroll
      for (int r = 0; r < 4; ++r) {
        int row = m0 + wm * 64 + mf * 16 + (l >> 4) * 4 + r;
        int col = n0 + wn * 64 + nf * 16 + (l & 15);
        out[(size_t)row * NDOUT + col] = acc[mf][nf][r];
      }
}

// ---------------------------------------------------------------------------
extern "C" void kernel_launch(void* const* d_in, const int* in_sizes, int n_in,
                              void* d_out, int out_size, void* d_ws, size_t ws_size,
                              hipStream_t stream) {
  const float* inputs = (const float*)d_in[0];   // (B, C, 16) f32
  const float* cents  = (const float*)d_in[1];   // (C, K, 16) f32
  const float* W      = (const float*)d_in[2];   // (512, 512) f32

  float* out = (float*)d_out;
  float* negout   = out + (size_t)NB * NDOUT;            // (B, C)
  float* codefout = negout + (size_t)NB * NC;            // (B, C) as float values

  unsigned short* Wt     = (unsigned short*)d_ws;                          // 512 KiB
  unsigned short* centsB = (unsigned short*)((char*)d_ws + 512 * 1024);    // 256 KiB
  int* codeint           = (int*)((char*)d_ws + (1 << 20));                // 4 MiB
  f2v* centsP            = (f2v*)((char*)d_ws + 5 * (1 << 20));            // 512 KiB

  k_prep<<<320, 256, 0, stream>>>(W, cents, Wt, centsB, centsP);
  k_phase1<<<dim3(NB / 512, NC), 256, 0, stream>>>(inputs, centsP, negout, codefout, codeint);
  k_gemm<<<dim3(NB / 128, NDOUT / 128), 256, 0, stream>>>(centsB, codeint, Wt, out);
}